// Round 5
// baseline (103.772 us; speedup 1.0000x reference)
//
#include <hip/hip_runtime.h>
#include <cstddef>

typedef _Float16 f16;
typedef __attribute__((ext_vector_type(2))) _Float16 f16x2;
typedef __attribute__((ext_vector_type(4))) _Float16 f16x4;
typedef __attribute__((ext_vector_type(8))) _Float16 f16x8;
typedef __attribute__((ext_vector_type(4))) float fx4;

union f16x8u { f16x8 v; f16x2 h[4]; };

#define BS   2
#define NPTS 512
#define DIN  256
#define NH   8
#define DH   64
#define HD   512   // NH*DH

// ---------------------------------------------------------------------------
// K_A: projections (blocks 0..383) + adj passthrough (blocks 384..511).
// Proj: mt = blk&15 (64-row M tile of 1024), nt = (blk>>4)&7 (64-col N tile),
// wz = blk>>7 (which W).  A-tile from x (f32->f16 in staging), B-tile from W
// (f32->f16 transposed in staging), 64x64 MFMA tile, K=256 in two 128 chunks.
// wz=0 -> src16 + srcT16, wz=1 -> tgt16, wz=2 -> skipf (f32)
// ---------------------------------------------------------------------------
__global__ __launch_bounds__(256) void proj_kernel(
    const float* __restrict__ x, const float* __restrict__ W0,
    const float* __restrict__ W1, const float* __restrict__ W2,
    const int* __restrict__ adj,
    f16* __restrict__ src16, f16* __restrict__ srcT16, f16* __restrict__ tgt16,
    float* __restrict__ skipf, float* __restrict__ out_adj)
{
    __shared__ f16 Alds[64 * 136];   // 17408 B
    __shared__ f16 Blds[64 * 136];   // 17408 B
    const int blk = blockIdx.x;
    const int t = threadIdx.x;
    const int lane = t & 63, wv = t >> 6;
    const int l15 = lane & 15, quad = lane >> 4;

    if (blk >= 384) {
        // adj passthrough: 128 blocks x 4096 ints -> float
        int id = blk - 384;
        #pragma unroll
        for (int j = 0; j < 4; ++j) {
            int idx = id * 4096 + (t + j * 256) * 4;
            int4 v = *(const int4*)(adj + idx);
            float4 fv = {(float)v.x, (float)v.y, (float)v.z, (float)v.w};
            *(float4*)(out_adj + idx) = fv;
        }
        return;
    }

    const int mt = blk & 15, nt = (blk >> 4) & 7, wz = blk >> 7;
    const float* W = (wz == 0) ? W0 : ((wz == 1) ? W1 : W2);
    const int moff = (wv & 1) * 32, noff = (wv >> 1) * 32;

    fx4 acc[2][2];
    #pragma unroll
    for (int fi = 0; fi < 2; ++fi)
        #pragma unroll
        for (int fj = 0; fj < 2; ++fj)
            acc[fi][fj] = (fx4){0.f, 0.f, 0.f, 0.f};

    for (int kk = 0; kk < 2; ++kk) {
        if (kk) __syncthreads();
        // A-tile: 64 rows x 128 k from x (f32), convert to f16
        #pragma unroll
        for (int i = 0; i < 8; ++i) {
            int idx = t + i * 256;
            int row = idx >> 5, c = idx & 31;          // c*4 = k offset
            float4 v = *(const float4*)(x + (size_t)(mt * 64 + row) * DIN
                                          + kk * 128 + c * 4);
            f16x4 h = {(f16)v.x, (f16)v.y, (f16)v.z, (f16)v.w};
            *(f16x4*)&Alds[row * 136 + c * 4] = h;
        }
        // B-tile: W rows k (128) x cols n (64), transposed into LDS [n][k]
        #pragma unroll
        for (int i = 0; i < 8; ++i) {
            int idx = t + i * 256;
            int k = idx >> 4, c = idx & 15;            // c*4 = n offset
            float4 v = *(const float4*)(W + (size_t)(kk * 128 + k) * HD
                                          + nt * 64 + c * 4);
            Blds[(c * 4 + 0) * 136 + k] = (f16)v.x;
            Blds[(c * 4 + 1) * 136 + k] = (f16)v.y;
            Blds[(c * 4 + 2) * 136 + k] = (f16)v.z;
            Blds[(c * 4 + 3) * 136 + k] = (f16)v.w;
        }
        __syncthreads();
        #pragma unroll
        for (int ks = 0; ks < 4; ++ks) {
            f16x8 aF[2], bF[2];
            #pragma unroll
            for (int f = 0; f < 2; ++f) {
                aF[f] = *(const f16x8*)&Alds[(moff + f * 16 + l15) * 136
                                             + ks * 32 + quad * 8];
                bF[f] = *(const f16x8*)&Blds[(noff + f * 16 + l15) * 136
                                             + ks * 32 + quad * 8];
            }
            #pragma unroll
            for (int fi = 0; fi < 2; ++fi)
                #pragma unroll
                for (int fj = 0; fj < 2; ++fj)
                    acc[fi][fj] = __builtin_amdgcn_mfma_f32_16x16x32_f16(
                        aF[fi], bF[fj], acc[fi][fj], 0, 0, 0);
        }
    }

    // epilogue: C/D layout col=lane&15, row=quad*4+reg
    #pragma unroll
    for (int fi = 0; fi < 2; ++fi)
        #pragma unroll
        for (int fj = 0; fj < 2; ++fj)
            #pragma unroll
            for (int i = 0; i < 4; ++i) {
                int rowg = mt * 64 + moff + fi * 16 + quad * 4 + i; // b*512+n
                int colg = nt * 64 + noff + fj * 16 + l15;          // h*64+d
                float v = acc[fi][fj][i];
                if (wz == 2) {
                    skipf[(size_t)rowg * HD + colg] = v;
                } else {
                    int bb = rowg >> 9, n = rowg & 511;
                    int hh = colg >> 6, d = colg & 63;
                    size_t bh = (size_t)bb * NH + hh;
                    if (wz == 0) {
                        src16[(bh * NPTS + n) * DH + d] = (f16)v;
                        srcT16[(bh * DH + d) * NPTS + n] = (f16)v;
                    } else {
                        tgt16[(bh * NPTS + n) * DH + d] = (f16)v;
                    }
                }
            }
}

// ---------------------------------------------------------------------------
// K_B: fused attention.  512 blocks (32 row-tiles x 8 h x 2 b), 4 waves.
// Block = 16 rows x all 512 m for one (b,h).  Wave owns 4 rows.
// ---------------------------------------------------------------------------
__global__ __launch_bounds__(256) void attn_kernel(
    const f16* __restrict__ src16, const f16* __restrict__ srcT16,
    const f16* __restrict__ tgt16, const float* __restrict__ a,
    const float* __restrict__ skipf, const float* __restrict__ bias,
    const int* __restrict__ adj, float* __restrict__ out)
{
    __shared__ f16 tgt_lds[256 * 72];   // 36864 B, stride 72 (36 dw = 4 mod 32)
    __shared__ f16 p_lds[16 * 520];     // 16640 B, stride 520 (260 dw = 4 mod 32)
    __shared__ f16 src_lds[16 * 64];    //  2048 B (broadcast reads)
    __shared__ f16 a_lds[64];

    const int t = threadIdx.x;
    const int lane = t & 63, wv = t >> 6;
    const int blk = blockIdx.x;
    const int tile = blk & 31;
    const int h = (blk >> 5) & 7, b = blk >> 8;
    const int n0 = tile * 16;
    const int bh = b * NH + h;
    const f16x2 slope2 = {(f16)0.2f, (f16)0.2f};

    // stage src rows (16x64) + a (64, f32->f16) once
    if (t < 128) {
        int row = t >> 3, seg = t & 7;
        *(f16x8*)&src_lds[row * 64 + seg * 8] =
            *(const f16x8*)(src16 + ((size_t)bh * NPTS + n0 + row) * DH + seg * 8);
    } else if (t < 192) {
        a_lds[t - 128] = (f16)a[h * DH + (t - 128)];
    }

    const int r0 = n0 + wv * 4;

    for (int mtile = 0; mtile < 2; ++mtile) {
        __syncthreads();
        // stage tgt tile: 256 rows x 64 d = 2048 f16x8 chunks; 256 thr x 8
        #pragma unroll
        for (int i = 0; i < 8; ++i) {
            int idx = t + i * 256;
            int row = idx >> 3, seg = idx & 7;
            *(f16x8*)&tgt_lds[row * 72 + seg * 8] =
                *(const f16x8*)(tgt16 + ((size_t)bh * NPTS + mtile * 256 + row) * DH
                                + seg * 8);
        }
        __syncthreads();

        float sc[4][4] = {{0.f, 0.f, 0.f, 0.f}, {0.f, 0.f, 0.f, 0.f},
                          {0.f, 0.f, 0.f, 0.f}, {0.f, 0.f, 0.f, 0.f}};
        for (int st = 0; st < 8; ++st) {   // 8 d-chunks of 8
            f16x8u a8; a8.v = *(const f16x8*)&a_lds[st * 8];
            f16x8u s8[4];
            #pragma unroll
            for (int r = 0; r < 4; ++r)
                s8[r].v = *(const f16x8*)&src_lds[(wv * 4 + r) * 64 + st * 8];
            #pragma unroll
            for (int jj = 0; jj < 4; ++jj) {
                int ml = jj * 64 + lane;
                f16x8u t8; t8.v = *(const f16x8*)&tgt_lds[ml * 72 + st * 8];
                #pragma unroll
                for (int c = 0; c < 4; ++c) {
                    f16x2 t2 = t8.h[c];
                    f16x2 a2 = a8.h[c];
                    #pragma unroll
                    for (int r = 0; r < 4; ++r) {
                        f16x2 z = s8[r].h[c] + t2;
                        f16x2 zl = __builtin_elementwise_max(z, z * slope2);
                        sc[r][jj] = __builtin_amdgcn_fdot2(a2, zl, sc[r][jj], false);
                    }
                }
            }
        }
        // mask + store raw f16 scores
        #pragma unroll
        for (int r = 0; r < 4; ++r) {
            #pragma unroll
            for (int jj = 0; jj < 4; ++jj) {
                int m = mtile * 256 + jj * 64 + lane;
                int av = adj[((size_t)b * NPTS + r0 + r) * NPTS + m];
                float s = (av > 0) ? sc[r][jj] : -1e30f;  // f16 -> -inf, exp -> 0
                p_lds[(wv * 4 + r) * 520 + m] = (f16)s;
            }
        }
    }
    __syncthreads();

    // softmax: wave wv owns rows wv*4 .. wv*4+3; each lane holds 8 scores
    #pragma unroll
    for (int r = 0; r < 4; ++r) {
        int row = wv * 4 + r;
        f16x8 v = *(const f16x8*)&p_lds[row * 520 + lane * 8];
        float vf[8];
        #pragma unroll
        for (int i = 0; i < 8; ++i) vf[i] = (float)v[i];
        float mx = vf[0];
        #pragma unroll
        for (int i = 1; i < 8; ++i) mx = fmaxf(mx, vf[i]);
        for (int msk = 1; msk < 64; msk <<= 1) mx = fmaxf(mx, __shfl_xor(mx, msk, 64));
        float l = 0.f;
        #pragma unroll
        for (int i = 0; i < 8; ++i) { vf[i] = __expf(vf[i] - mx); l += vf[i]; }
        for (int msk = 1; msk < 64; msk <<= 1) l += __shfl_xor(l, msk, 64);
        float inv = 1.0f / l;
        f16x8 pv;
        #pragma unroll
        for (int i = 0; i < 8; ++i) pv[i] = (f16)(vf[i] * inv);
        *(f16x8*)&p_lds[row * 520 + lane * 8] = pv;
    }
    __syncthreads();

    // PV via MFMA: wave wv handles d-range [wv*16, wv*16+16), all 16 rows
    const int l15 = lane & 15, quad = lane >> 4;
    fx4 acc = {0.f, 0.f, 0.f, 0.f};
    const f16* vb = srcT16 + ((size_t)bh * DH + wv * 16 + l15) * NPTS;
    #pragma unroll
    for (int ks = 0; ks < 16; ++ks) {
        f16x8 a8 = *(const f16x8*)&p_lds[l15 * 520 + ks * 32 + quad * 8];
        f16x8 b8 = *(const f16x8*)(vb + ks * 32 + quad * 8);
        acc = __builtin_amdgcn_mfma_f32_16x16x32_f16(a8, b8, acc, 0, 0, 0);
    }
    // epilogue: + skip + bias, ELU
    #pragma unroll
    for (int i = 0; i < 4; ++i) {
        int ng = n0 + quad * 4 + i;
        int col = h * DH + wv * 16 + l15;
        size_t oi = ((size_t)b * NPTS + ng) * HD + col;
        float val = acc[i] + skipf[oi] + bias[col];
        out[oi] = (val > 0.f) ? val : __expf(val) - 1.f;
    }
}

// ---------------------------------------------------------------------------
extern "C" void kernel_launch(void* const* d_in, const int* in_sizes, int n_in,
                              void* d_out, int out_size, void* d_ws, size_t ws_size,
                              hipStream_t stream) {
    const float* x     = (const float*)d_in[0];
    const int*   adj   = (const int*)d_in[1];
    const float* Wsrc  = (const float*)d_in[2];
    const float* Wtgt  = (const float*)d_in[3];
    const float* Wskip = (const float*)d_in[4];
    const float* a     = (const float*)d_in[5];
    const float* bias  = (const float*)d_in[6];

    float* out = (float*)d_out;                       // 524288 f32 (bs,n,H*d)
    float* out_adj = out + (size_t)BS * NPTS * NPTS;  // adj echoed as float

    char* wsb = (char*)d_ws;
    f16*   src16  = (f16*)(wsb + 0x000000);           // 1 MB  [b][h][n][d]
    f16*   srcT16 = (f16*)(wsb + 0x100000);           // 1 MB  [b][h][d][n]
    f16*   tgt16  = (f16*)(wsb + 0x200000);           // 1 MB  [b][h][m][d]
    float* skipf  = (float*)(wsb + 0x300000);         // 2 MB  [b*n][h*64+d]

    proj_kernel<<<512, 256, 0, stream>>>(x, Wsrc, Wtgt, Wskip, adj,
                                         src16, srcT16, tgt16, skipf, out_adj);
    attn_kernel<<<512, 256, 0, stream>>>(src16, srcT16, tgt16, a,
                                         skipf, bias, adj, out);
}

// Round 6
// 101.880 us; speedup vs baseline: 1.0186x; 1.0186x over previous
//
#include <hip/hip_runtime.h>
#include <cstddef>

typedef _Float16 f16;
typedef __attribute__((ext_vector_type(2))) _Float16 f16x2;
typedef __attribute__((ext_vector_type(4))) _Float16 f16x4;
typedef __attribute__((ext_vector_type(8))) _Float16 f16x8;
typedef __attribute__((ext_vector_type(4))) float fx4;

union f16x8u { f16x8 v; f16x2 h[4]; };

__device__ __forceinline__ f16x2 pk_abs(f16x2 v) {
    unsigned u = __builtin_bit_cast(unsigned, v) & 0x7FFF7FFFu;
    return __builtin_bit_cast(f16x2, u);
}

#define BS   2
#define NPTS 512
#define DIN  256
#define NH   8
#define DH   64
#define HD   512   // NH*DH

// ---------------------------------------------------------------------------
// K_A: projections (blocks 0..383) + adj passthrough (blocks 384..511).
// Proj: mt = blk&15 (64-row M tile of 1024), nt = (blk>>4)&7 (64-col N tile),
// wz = blk>>7 (which W).  A-tile from x (f32->f16 in staging), B-tile from W
// (f32->f16 transposed in staging), 64x64 MFMA tile, K=256 in two 128 chunks.
// wz=0 -> src16 + srcT16, wz=1 -> tgt16, wz=2 -> skipf (f32)
// ---------------------------------------------------------------------------
__global__ __launch_bounds__(256) void proj_kernel(
    const float* __restrict__ x, const float* __restrict__ W0,
    const float* __restrict__ W1, const float* __restrict__ W2,
    const int* __restrict__ adj,
    f16* __restrict__ src16, f16* __restrict__ srcT16, f16* __restrict__ tgt16,
    float* __restrict__ skipf, float* __restrict__ out_adj)
{
    __shared__ f16 Alds[64 * 136];   // 17408 B
    __shared__ f16 Blds[64 * 136];   // 17408 B
    const int blk = blockIdx.x;
    const int t = threadIdx.x;
    const int lane = t & 63, wv = t >> 6;
    const int l15 = lane & 15, quad = lane >> 4;

    if (blk >= 384) {
        // adj passthrough: 128 blocks x 4096 ints -> float
        int id = blk - 384;
        #pragma unroll
        for (int j = 0; j < 4; ++j) {
            int idx = id * 4096 + (t + j * 256) * 4;
            int4 v = *(const int4*)(adj + idx);
            float4 fv = {(float)v.x, (float)v.y, (float)v.z, (float)v.w};
            *(float4*)(out_adj + idx) = fv;
        }
        return;
    }

    const int mt = blk & 15, nt = (blk >> 4) & 7, wz = blk >> 7;
    const float* W = (wz == 0) ? W0 : ((wz == 1) ? W1 : W2);
    const int moff = (wv & 1) * 32, noff = (wv >> 1) * 32;

    fx4 acc[2][2];
    #pragma unroll
    for (int fi = 0; fi < 2; ++fi)
        #pragma unroll
        for (int fj = 0; fj < 2; ++fj)
            acc[fi][fj] = (fx4){0.f, 0.f, 0.f, 0.f};

    for (int kk = 0; kk < 2; ++kk) {
        if (kk) __syncthreads();
        // A-tile: 64 rows x 128 k from x (f32), convert to f16
        #pragma unroll
        for (int i = 0; i < 8; ++i) {
            int idx = t + i * 256;
            int row = idx >> 5, c = idx & 31;          // c*4 = k offset
            float4 v = *(const float4*)(x + (size_t)(mt * 64 + row) * DIN
                                          + kk * 128 + c * 4);
            f16x4 h = {(f16)v.x, (f16)v.y, (f16)v.z, (f16)v.w};
            *(f16x4*)&Alds[row * 136 + c * 4] = h;
        }
        // B-tile: W rows k (128) x cols n (64), transposed into LDS [n][k]
        #pragma unroll
        for (int i = 0; i < 8; ++i) {
            int idx = t + i * 256;
            int k = idx >> 4, c = idx & 15;            // c*4 = n offset
            float4 v = *(const float4*)(W + (size_t)(kk * 128 + k) * HD
                                          + nt * 64 + c * 4);
            Blds[(c * 4 + 0) * 136 + k] = (f16)v.x;
            Blds[(c * 4 + 1) * 136 + k] = (f16)v.y;
            Blds[(c * 4 + 2) * 136 + k] = (f16)v.z;
            Blds[(c * 4 + 3) * 136 + k] = (f16)v.w;
        }
        __syncthreads();
        #pragma unroll
        for (int ks = 0; ks < 4; ++ks) {
            f16x8 aF[2], bF[2];
            #pragma unroll
            for (int f = 0; f < 2; ++f) {
                aF[f] = *(const f16x8*)&Alds[(moff + f * 16 + l15) * 136
                                             + ks * 32 + quad * 8];
                bF[f] = *(const f16x8*)&Blds[(noff + f * 16 + l15) * 136
                                             + ks * 32 + quad * 8];
            }
            #pragma unroll
            for (int fi = 0; fi < 2; ++fi)
                #pragma unroll
                for (int fj = 0; fj < 2; ++fj)
                    acc[fi][fj] = __builtin_amdgcn_mfma_f32_16x16x32_f16(
                        aF[fi], bF[fj], acc[fi][fj], 0, 0, 0);
        }
    }

    // epilogue: C/D layout col=lane&15, row=quad*4+reg
    #pragma unroll
    for (int fi = 0; fi < 2; ++fi)
        #pragma unroll
        for (int fj = 0; fj < 2; ++fj)
            #pragma unroll
            for (int i = 0; i < 4; ++i) {
                int rowg = mt * 64 + moff + fi * 16 + quad * 4 + i; // b*512+n
                int colg = nt * 64 + noff + fj * 16 + l15;          // h*64+d
                float v = acc[fi][fj][i];
                if (wz == 2) {
                    skipf[(size_t)rowg * HD + colg] = v;
                } else {
                    int bb = rowg >> 9, n = rowg & 511;
                    int hh = colg >> 6, d = colg & 63;
                    size_t bh = (size_t)bb * NH + hh;
                    if (wz == 0) {
                        src16[(bh * NPTS + n) * DH + d] = (f16)v;
                        srcT16[(bh * DH + d) * NPTS + n] = (f16)v;
                    } else {
                        tgt16[(bh * NPTS + n) * DH + d] = (f16)v;
                    }
                }
            }
}

// ---------------------------------------------------------------------------
// K_B: fused attention.  512 blocks (32 row-tiles x 8 h x 2 b), 4 waves.
// Block = 16 rows x all 512 m for one (b,h).  Wave owns 4 rows.
// Scores use leaky(z) = 0.6z + 0.4|z|:
//   score(i,j) = 0.6(a.s_i) + 0.6(a.t_j) + sum_d (0.4 a_d)|s_d + t_d|
// Rank-1 terms A6_i / B6_j via fdot2; |z| inner loop = pk_add + v_and + fdot2
// (3 VALU per 2 MACs, f32 accumulation).
// ---------------------------------------------------------------------------
__global__ __launch_bounds__(256) void attn_kernel(
    const f16* __restrict__ src16, const f16* __restrict__ srcT16,
    const f16* __restrict__ tgt16, const float* __restrict__ a,
    const float* __restrict__ skipf, const float* __restrict__ bias,
    const int* __restrict__ adj, float* __restrict__ out)
{
    __shared__ f16 tgt_lds[256 * 72];   // 36864 B, stride 72 (36 dw = 4 mod 32)
    __shared__ f16 p_lds[16 * 520];     // 16640 B, stride 520 (260 dw = 4 mod 32)
    __shared__ f16 src_lds[16 * 64];    //  2048 B (broadcast reads)
    __shared__ f16 a_lds[64];           // a
    __shared__ f16 c_lds[64];           // 0.4*a

    const int t = threadIdx.x;
    const int lane = t & 63, wv = t >> 6;
    const int blk = blockIdx.x;
    const int tile = blk & 31;
    const int h = (blk >> 5) & 7, b = blk >> 8;
    const int n0 = tile * 16;
    const int bh = b * NH + h;

    // stage src rows (16x64) + a/c (64 each, f32->f16) once
    if (t < 128) {
        int row = t >> 3, seg = t & 7;
        *(f16x8*)&src_lds[row * 64 + seg * 8] =
            *(const f16x8*)(src16 + ((size_t)bh * NPTS + n0 + row) * DH + seg * 8);
    } else if (t < 192) {
        float av = a[h * DH + (t - 128)];
        a_lds[t - 128] = (f16)av;
        c_lds[t - 128] = (f16)(0.4f * av);
    }
    __syncthreads();

    // A6[r] = 0.6 * (a . s_row) — each lane computes its wave's 4 rows
    float A6[4];
    #pragma unroll
    for (int r = 0; r < 4; ++r) {
        float acc = 0.f;
        #pragma unroll
        for (int st = 0; st < 8; ++st) {
            f16x8u a8; a8.v = *(const f16x8*)&a_lds[st * 8];
            f16x8u s8; s8.v = *(const f16x8*)&src_lds[(wv * 4 + r) * 64 + st * 8];
            #pragma unroll
            for (int c = 0; c < 4; ++c)
                acc = __builtin_amdgcn_fdot2(a8.h[c], s8.h[c], acc, false);
        }
        A6[r] = 0.6f * acc;
    }

    const int r0 = n0 + wv * 4;

    for (int mtile = 0; mtile < 2; ++mtile) {
        __syncthreads();
        // stage tgt tile: 256 rows x 64 d = 2048 f16x8 chunks; 256 thr x 8
        #pragma unroll
        for (int i = 0; i < 8; ++i) {
            int idx = t + i * 256;
            int row = idx >> 3, seg = idx & 7;
            *(f16x8*)&tgt_lds[row * 72 + seg * 8] =
                *(const f16x8*)(tgt16 + ((size_t)bh * NPTS + mtile * 256 + row) * DH
                                + seg * 8);
        }
        __syncthreads();

        float sc[4][4] = {{0.f, 0.f, 0.f, 0.f}, {0.f, 0.f, 0.f, 0.f},
                          {0.f, 0.f, 0.f, 0.f}, {0.f, 0.f, 0.f, 0.f}};
        float Bacc[4] = {0.f, 0.f, 0.f, 0.f};   // a . t_j (per jj), scaled later
        for (int st = 0; st < 8; ++st) {   // 8 d-chunks of 8
            f16x8u a8; a8.v = *(const f16x8*)&a_lds[st * 8];
            f16x8u c8; c8.v = *(const f16x8*)&c_lds[st * 8];
            f16x8u s8[4];
            #pragma unroll
            for (int r = 0; r < 4; ++r)
                s8[r].v = *(const f16x8*)&src_lds[(wv * 4 + r) * 64 + st * 8];
            #pragma unroll
            for (int jj = 0; jj < 4; ++jj) {
                int ml = jj * 64 + lane;
                f16x8u t8; t8.v = *(const f16x8*)&tgt_lds[ml * 72 + st * 8];
                #pragma unroll
                for (int c = 0; c < 4; ++c) {
                    f16x2 t2 = t8.h[c];
                    Bacc[jj] = __builtin_amdgcn_fdot2(a8.h[c], t2, Bacc[jj], false);
                    #pragma unroll
                    for (int r = 0; r < 4; ++r) {
                        f16x2 z = s8[r].h[c] + t2;
                        sc[r][jj] = __builtin_amdgcn_fdot2(c8.h[c], pk_abs(z),
                                                           sc[r][jj], false);
                    }
                }
            }
        }
        // combine rank-1 terms + mask, store raw f16 scores
        #pragma unroll
        for (int r = 0; r < 4; ++r) {
            #pragma unroll
            for (int jj = 0; jj < 4; ++jj) {
                int m = mtile * 256 + jj * 64 + lane;
                int av = adj[((size_t)b * NPTS + r0 + r) * NPTS + m];
                float s = sc[r][jj] + A6[r] + 0.6f * Bacc[jj];
                s = (av > 0) ? s : -1e30f;   // f16 -> -inf, exp -> 0
                p_lds[(wv * 4 + r) * 520 + m] = (f16)s;
            }
        }
    }
    __syncthreads();

    // softmax: wave wv owns rows wv*4 .. wv*4+3; each lane holds 8 scores
    #pragma unroll
    for (int r = 0; r < 4; ++r) {
        int row = wv * 4 + r;
        f16x8 v = *(const f16x8*)&p_lds[row * 520 + lane * 8];
        float vf[8];
        #pragma unroll
        for (int i = 0; i < 8; ++i) vf[i] = (float)v[i];
        float mx = vf[0];
        #pragma unroll
        for (int i = 1; i < 8; ++i) mx = fmaxf(mx, vf[i]);
        for (int msk = 1; msk < 64; msk <<= 1) mx = fmaxf(mx, __shfl_xor(mx, msk, 64));
        float l = 0.f;
        #pragma unroll
        for (int i = 0; i < 8; ++i) { vf[i] = __expf(vf[i] - mx); l += vf[i]; }
        for (int msk = 1; msk < 64; msk <<= 1) l += __shfl_xor(l, msk, 64);
        float inv = 1.0f / l;
        f16x8 pv;
        #pragma unroll
        for (int i = 0; i < 8; ++i) pv[i] = (f16)(vf[i] * inv);
        *(f16x8*)&p_lds[row * 520 + lane * 8] = pv;
    }
    __syncthreads();

    // PV via MFMA: wave wv handles d-range [wv*16, wv*16+16), all 16 rows
    const int l15 = lane & 15, quad = lane >> 4;
    fx4 acc = {0.f, 0.f, 0.f, 0.f};
    const f16* vb = srcT16 + ((size_t)bh * DH + wv * 16 + l15) * NPTS;
    #pragma unroll
    for (int ks = 0; ks < 16; ++ks) {
        f16x8 a8 = *(const f16x8*)&p_lds[l15 * 520 + ks * 32 + quad * 8];
        f16x8 b8 = *(const f16x8*)(vb + ks * 32 + quad * 8);
        acc = __builtin_amdgcn_mfma_f32_16x16x32_f16(a8, b8, acc, 0, 0, 0);
    }
    // epilogue: + skip + bias, ELU
    #pragma unroll
    for (int i = 0; i < 4; ++i) {
        int ng = n0 + quad * 4 + i;
        int col = h * DH + wv * 16 + l15;
        size_t oi = ((size_t)b * NPTS + ng) * HD + col;
        float val = acc[i] + skipf[oi] + bias[col];
        out[oi] = (val > 0.f) ? val : __expf(val) - 1.f;
    }
}

// ---------------------------------------------------------------------------
extern "C" void kernel_launch(void* const* d_in, const int* in_sizes, int n_in,
                              void* d_out, int out_size, void* d_ws, size_t ws_size,
                              hipStream_t stream) {
    const float* x     = (const float*)d_in[0];
    const int*   adj   = (const int*)d_in[1];
    const float* Wsrc  = (const float*)d_in[2];
    const float* Wtgt  = (const float*)d_in[3];
    const float* Wskip = (const float*)d_in[4];
    const float* a     = (const float*)d_in[5];
    const float* bias  = (const float*)d_in[6];

    float* out = (float*)d_out;                       // 524288 f32 (bs,n,H*d)
    float* out_adj = out + (size_t)BS * NPTS * NPTS;  // adj echoed as float

    char* wsb = (char*)d_ws;
    f16*   src16  = (f16*)(wsb + 0x000000);           // 1 MB  [b][h][n][d]
    f16*   srcT16 = (f16*)(wsb + 0x100000);           // 1 MB  [b][h][d][n]
    f16*   tgt16  = (f16*)(wsb + 0x200000);           // 1 MB  [b][h][m][d]
    float* skipf  = (float*)(wsb + 0x300000);         // 2 MB  [b*n][h*64+d]

    proj_kernel<<<512, 256, 0, stream>>>(x, Wsrc, Wtgt, Wskip, adj,
                                         src16, srcT16, tgt16, skipf, out_adj);
    attn_kernel<<<512, 256, 0, stream>>>(src16, srcT16, tgt16, a,
                                         skipf, bias, adj, out);
}